// Round 1
// baseline (223.991 us; speedup 1.0000x reference)
//
#include <hip/hip_runtime.h>
#include <hip/hip_bf16.h>
#include <stdint.h>

typedef __bf16 bf16_t;
typedef __bf16 bf16x4 __attribute__((ext_vector_type(4)));
typedef __bf16 bf16x8 __attribute__((ext_vector_type(8)));
typedef float  f32x4  __attribute__((ext_vector_type(4)));

// ---- workspace layout (bytes) ----
static constexpr size_t WT_OFF = 0;                    // Wt bf16 [384][1024] = 768 KB
static constexpr size_t Q_OFF  = (size_t)1 << 20;      // q bf16 [16384][128] = 4 MB
static constexpr size_t K_OFF  = Q_OFF + ((size_t)4 << 20);
static constexpr size_t VT_OFF = K_OFF + ((size_t)4 << 20);  // vT bf16 [8][128][2048] = 4 MB

__device__ __forceinline__ void g2lds16(const void* g, void* l) {
  __builtin_amdgcn_global_load_lds(
      (__attribute__((address_space(1))) void*)(g),
      (__attribute__((address_space(3))) void*)(l), 16, 0, 0);
}

// ---------------- W transpose: W[1024][128] fp32 -> Wt[384][1024] bf16 ----------------
__global__ __launch_bounds__(256) void wt_kernel(const float* __restrict__ Wq,
                                                 const float* __restrict__ Wk,
                                                 const float* __restrict__ Wv,
                                                 bf16_t* __restrict__ wt) {
  __shared__ float tile[64][129];
  int wi = blockIdx.x >> 4;   // 0..2
  int ct = blockIdx.x & 15;   // 0..15 -> c0
  const float* W = (wi == 0) ? Wq : ((wi == 1) ? Wk : Wv);
  int c0 = ct * 64;
  int tid = threadIdx.x;
  for (int i = 0; i < 32; ++i) {
    int idx = i * 256 + tid;
    int c = idx >> 7, n = idx & 127;
    tile[c][n] = W[(size_t)(c0 + c) * 128 + n];   // coalesced read
  }
  __syncthreads();
  for (int i = 0; i < 32; ++i) {
    int idx = i * 256 + tid;
    int n = idx >> 6, c = idx & 63;
    wt[(size_t)(wi * 128 + n) * 1024 + c0 + c] = (bf16_t)tile[c][n];  // coalesced-ish write
  }
}

// ---------------- fused QKV projection: D = Wt · x^T  (per-wave 16 t-rows, all 384 n) ----
// A-frag: Wt[n=nf*16+lq][k contiguous]; B-frag: x[t0+lq][k contiguous] (fp32->bf16)
// D: row = n-local = grp*4+r, col = t-local = lq  -> Q/K packed 8B stores; V scalar -> vT[d][t]
__global__ __launch_bounds__(256) void proj_kernel(const float* __restrict__ x,
                                                   const bf16_t* __restrict__ wt,
                                                   bf16_t* __restrict__ q,
                                                   bf16_t* __restrict__ k,
                                                   bf16_t* __restrict__ vT) {
  int lane = threadIdx.x & 63;
  int wave = threadIdx.x >> 6;
  int lq = lane & 15, grp = lane >> 4;
  int t0 = (blockIdx.x * 4 + wave) * 16;
  int tg = t0 + lq;

  f32x4 acc[24];
#pragma unroll
  for (int i = 0; i < 24; ++i) acc[i] = (f32x4){0.f, 0.f, 0.f, 0.f};

  const float* xrow = x + (size_t)tg * 1024 + grp * 8;

  for (int ks = 0; ks < 32; ++ks) {
    int k0 = ks * 32;
    float4 xa = *(const float4*)(xrow + k0);
    float4 xb = *(const float4*)(xrow + k0 + 4);
    bf16x8 xf;
    xf[0] = (bf16_t)xa.x; xf[1] = (bf16_t)xa.y; xf[2] = (bf16_t)xa.z; xf[3] = (bf16_t)xa.w;
    xf[4] = (bf16_t)xb.x; xf[5] = (bf16_t)xb.y; xf[6] = (bf16_t)xb.z; xf[7] = (bf16_t)xb.w;
#pragma unroll
    for (int nf = 0; nf < 24; ++nf) {
      bf16x8 wf = *(const bf16x8*)(wt + (size_t)(nf * 16 + lq) * 1024 + k0 + grp * 8);
      acc[nf] = __builtin_amdgcn_mfma_f32_16x16x32_bf16(wf, xf, acc[nf], 0, 0, 0);
    }
  }

  // epilogue: nf 0..7 -> Q row-major, 8..15 -> K row-major, 16..23 -> vT[d][t]
#pragma unroll
  for (int nf = 0; nf < 16; ++nf) {
    bf16x4 o;
    o[0] = (bf16_t)acc[nf][0]; o[1] = (bf16_t)acc[nf][1];
    o[2] = (bf16_t)acc[nf][2]; o[3] = (bf16_t)acc[nf][3];
    int d = (nf & 7) * 16 + grp * 4;
    bf16_t* dst = (nf < 8) ? q : k;
    *(bf16x4*)(dst + (size_t)tg * 128 + d) = o;
  }
  int b = tg >> 11, tt = tg & 2047;
#pragma unroll
  for (int nf = 16; nf < 24; ++nf) {
#pragma unroll
    for (int r = 0; r < 4; ++r) {
      int d = (nf - 16) * 16 + grp * 4 + r;
      vT[(size_t)b * 128 * 2048 + (size_t)d * 2048 + tt] = (bf16_t)acc[nf][r];
    }
  }
}

// ---------------- flash attention: S^T = K·Q^T, online softmax, O^T = V^T·P^T --------
__global__ __launch_bounds__(256) void attn_kernel(const bf16_t* __restrict__ q,
                                                   const bf16_t* __restrict__ k,
                                                   const bf16_t* __restrict__ vT,
                                                   float* __restrict__ out) {
  __shared__ __align__(16) char lds[40 * 1024];
  char* Klds = lds;                 // [64][128] bf16, XOR-swizzled rows (256B)
  char* Vlds = lds + 16384;         // [128][64] bf16, XOR-swizzled rows (128B)
  char* Plds = lds + 32768 + (threadIdx.x >> 6) * 2048;  // per-wave 2KB packed P^T

  int lane = threadIdx.x & 63;
  int wave = threadIdx.x >> 6;
  int lq = lane & 15, grp = lane >> 4;
  int b = blockIdx.x >> 5, qt = blockIdx.x & 31;
  int q0 = qt * 64 + wave * 16;
  int tq = q0 + lq;                 // this lane's q row

  // Q fragments (B-operand for S^T): lane lq -> q row, slots = d
  bf16x8 qf[4];
  const bf16_t* qrow = q + ((size_t)b * 2048 + tq) * 128 + grp * 8;
#pragma unroll
  for (int ks = 0; ks < 4; ++ks) qf[ks] = *(const bf16x8*)(qrow + ks * 32);

  float mrun = -__builtin_inff();
  float lsum = 0.f;
  f32x4 accO[8];
#pragma unroll
  for (int i = 0; i < 8; ++i) accO[i] = (f32x4){0.f, 0.f, 0.f, 0.f};

  const float scale = 1.0f / 32.0f;   // C^-0.5
  const char* kbase = (const char*)(k + (size_t)b * 2048 * 128);
  const char* vbase = (const char*)(vT + (size_t)b * 128 * 2048);

  int ntiles = qt + 1;
  for (int it = 0; it < ntiles; ++it) {
    int kv0 = it * 64;
    __syncthreads();  // previous tile's compute done before overwrite
    // stage K tile [64][128] bf16: 16 x 1KB chunks, pre-swizzled global source
#pragma unroll
    for (int c = 0; c < 4; ++c) {
      int chunk = wave * 4 + c;
      int row = chunk * 4 + (lane >> 4);
      int colb = (lane & 15) * 16;
      const char* src = kbase + (size_t)(kv0 + row) * 256 + (colb ^ ((row & 7) << 4));
      g2lds16(src, Klds + chunk * 1024 + lane * 16);
    }
    // stage V^T tile [128][64] bf16
#pragma unroll
    for (int c = 0; c < 4; ++c) {
      int chunk = wave * 4 + c;
      int row = chunk * 8 + (lane >> 3);
      int colb = (lane & 7) * 16;
      const char* src = vbase + (size_t)row * 4096 + kv0 * 2 + (colb ^ ((row & 7) << 4));
      g2lds16(src, Vlds + chunk * 1024 + lane * 16);
    }
    __syncthreads();  // drains vmcnt: tiles ready

    // S^T = K · Q^T : 4 kv-frags x 4 k-steps
    f32x4 s[4];
#pragma unroll
    for (int i = 0; i < 4; ++i) s[i] = (f32x4){0.f, 0.f, 0.f, 0.f};
#pragma unroll
    for (int ks = 0; ks < 4; ++ks) {
#pragma unroll
      for (int mf = 0; mf < 4; ++mf) {
        int row = mf * 16 + lq;
        int colb = ks * 64 + grp * 16;
        bf16x8 kf = *(const bf16x8*)(Klds + row * 256 + (colb ^ ((row & 7) << 4)));
        s[mf] = __builtin_amdgcn_mfma_f32_16x16x32_bf16(kf, qf[ks], s[mf], 0, 0, 0);
      }
    }

    // online softmax; lane owns q-row tq, holds 16 kv values
    float z[4][4];
    float pmax = -__builtin_inff();
#pragma unroll
    for (int f = 0; f < 4; ++f) {
#pragma unroll
      for (int r = 0; r < 4; ++r) {
        int kv = kv0 + f * 16 + grp * 4 + r;
        float zz = s[f][r] * scale;
        zz = (kv <= tq) ? zz : -__builtin_inff();
        z[f][r] = zz;
        pmax = fmaxf(pmax, zz);
      }
    }
    pmax = fmaxf(pmax, __shfl_xor(pmax, 16, 64));
    pmax = fmaxf(pmax, __shfl_xor(pmax, 32, 64));
    float mnew = fmaxf(mrun, pmax);
    float corr = __expf(mrun - mnew);   // -inf -> 0 on first tile
    float p[4][4];
    float psum = 0.f;
#pragma unroll
    for (int f = 0; f < 4; ++f) {
#pragma unroll
      for (int r = 0; r < 4; ++r) {
        p[f][r] = __expf(z[f][r] - mnew);
        psum += p[f][r];
      }
    }
    psum += __shfl_xor(psum, 16, 64);
    psum += __shfl_xor(psum, 32, 64);
    lsum = lsum * corr + psum;
    mrun = mnew;
#pragma unroll
    for (int i = 0; i < 8; ++i) accO[i] *= corr;

    // pack P^T into wave-private LDS in exact B-operand order
#pragma unroll
    for (int f = 0; f < 4; ++f) {
      bf16x4 pw;
      pw[0] = (bf16_t)p[f][0]; pw[1] = (bf16_t)p[f][1];
      pw[2] = (bf16_t)p[f][2]; pw[3] = (bf16_t)p[f][3];
      *(bf16x4*)(Plds + ((f * 2 + (grp >> 1)) << 8) + lq * 16 + ((grp & 1) << 3)) = pw;
    }

    // O^T += V^T · P^T : 8 d-frags x 2 kv-steps
#pragma unroll
    for (int kc = 0; kc < 2; ++kc) {
      bf16x8 pf = *(const bf16x8*)(Plds + ((kc * 4 + grp) << 8) + lq * 16);
#pragma unroll
      for (int mf = 0; mf < 8; ++mf) {
        int row = mf * 16 + lq;
        int colb = kc * 64 + grp * 16;
        bf16x8 vf = *(const bf16x8*)(Vlds + row * 128 + (colb ^ ((row & 7) << 4)));
        accO[mf] = __builtin_amdgcn_mfma_f32_16x16x32_bf16(vf, pf, accO[mf], 0, 0, 0);
      }
    }
  }

  // epilogue: out[b][tq][d], d = mf*16 + grp*4 + r  -> float4 stores
  float inv = 1.0f / lsum;
  float* orow = out + ((size_t)b * 2048 + tq) * 128;
#pragma unroll
  for (int mf = 0; mf < 8; ++mf) {
    f32x4 o;
    o[0] = accO[mf][0] * inv; o[1] = accO[mf][1] * inv;
    o[2] = accO[mf][2] * inv; o[3] = accO[mf][3] * inv;
    *(f32x4*)(orow + mf * 16 + grp * 4) = o;
  }
}

extern "C" void kernel_launch(void* const* d_in, const int* in_sizes, int n_in,
                              void* d_out, int out_size, void* d_ws, size_t ws_size,
                              hipStream_t stream) {
  const float* x  = (const float*)d_in[0];
  const float* Wq = (const float*)d_in[1];
  const float* Wk = (const float*)d_in[2];
  const float* Wv = (const float*)d_in[3];
  float* out = (float*)d_out;
  char* ws = (char*)d_ws;

  bf16_t* wt = (bf16_t*)(ws + WT_OFF);
  bf16_t* qb = (bf16_t*)(ws + Q_OFF);
  bf16_t* kb = (bf16_t*)(ws + K_OFF);
  bf16_t* vT = (bf16_t*)(ws + VT_OFF);

  hipLaunchKernelGGL(wt_kernel, dim3(48), dim3(256), 0, stream, Wq, Wk, Wv, wt);
  hipLaunchKernelGGL(proj_kernel, dim3(256), dim3(256), 0, stream, x, wt, qb, kb, vT);
  hipLaunchKernelGGL(attn_kernel, dim3(256), dim3(256), 0, stream, qb, kb, vT, out);
}

// Round 2
// 177.920 us; speedup vs baseline: 1.2589x; 1.2589x over previous
//
#include <hip/hip_runtime.h>
#include <hip/hip_bf16.h>
#include <stdint.h>

typedef __bf16 bf16_t;
typedef __bf16 bf16x4 __attribute__((ext_vector_type(4)));
typedef __bf16 bf16x8 __attribute__((ext_vector_type(8)));
typedef float  f32x4  __attribute__((ext_vector_type(4)));

// ---- workspace layout (bytes) ----
static constexpr size_t WT_OFF = 0;                    // Wt bf16 [384][1024] = 768 KB
static constexpr size_t Q_OFF  = (size_t)1 << 20;      // q bf16 [16384][128] = 4 MB
static constexpr size_t K_OFF  = Q_OFF + ((size_t)4 << 20);
static constexpr size_t VT_OFF = K_OFF + ((size_t)4 << 20);  // vT bf16 [8][128][2048] = 4 MB

__device__ __forceinline__ void g2lds16(const void* g, void* l) {
  __builtin_amdgcn_global_load_lds(
      (__attribute__((address_space(1))) void*)(g),
      (__attribute__((address_space(3))) void*)(l), 16, 0, 0);
}

// ---------------- W transpose: W[1024][128] fp32 -> Wt[384][1024] bf16 ----------------
__global__ __launch_bounds__(256) void wt_kernel(const float* __restrict__ Wq,
                                                 const float* __restrict__ Wk,
                                                 const float* __restrict__ Wv,
                                                 bf16_t* __restrict__ wt) {
  __shared__ float tile[64][129];
  int wi = blockIdx.x >> 4;   // 0..2
  int ct = blockIdx.x & 15;   // 0..15 -> c0
  const float* W = (wi == 0) ? Wq : ((wi == 1) ? Wk : Wv);
  int c0 = ct * 64;
  int tid = threadIdx.x;
  for (int i = 0; i < 32; ++i) {
    int idx = i * 256 + tid;
    int c = idx >> 7, n = idx & 127;
    tile[c][n] = W[(size_t)(c0 + c) * 128 + n];   // coalesced read
  }
  __syncthreads();
  for (int i = 0; i < 32; ++i) {
    int idx = i * 256 + tid;
    int n = idx >> 6, c = idx & 63;
    wt[(size_t)(wi * 128 + n) * 1024 + c0 + c] = (bf16_t)tile[c][n];  // coalesced-ish write
  }
}

// ---------------- fused QKV projection v2 ------------------------------------------
// Grid 768 = 256 t-tiles x 3 slices (slice 0=Q,1=K,2=V). Block: 64 t-rows, 128 n.
// 4 waves share the wt slice (L1/L2 reuse), each owns 16 t-rows. No LDS.
// A-frag: wt[n0+nf*16+lq][k contig]; B-frag: x[tg][k contig] cvt fp32->bf16, prefetched.
// D: row = n-local = grp*4+r, col = t-local = lq.
__global__ __launch_bounds__(256, 3) void proj_kernel(const float* __restrict__ x,
                                                      const bf16_t* __restrict__ wt,
                                                      bf16_t* __restrict__ q,
                                                      bf16_t* __restrict__ k,
                                                      bf16_t* __restrict__ vT) {
  // XCD-bijective chunked swizzle: 768 % 8 == 0, 96 blocks per XCD
  int wgid = (blockIdx.x & 7) * 96 + (blockIdx.x >> 3);
  int t_tile = wgid / 3;
  int slice = wgid % 3;          // 0=Q, 1=K, 2=V
  int n0 = slice * 128;

  int lane = threadIdx.x & 63;
  int wave = threadIdx.x >> 6;
  int lq = lane & 15, grp = lane >> 4;
  int tg = t_tile * 64 + wave * 16 + lq;

  f32x4 acc[8];
#pragma unroll
  for (int i = 0; i < 8; ++i) acc[i] = (f32x4){0.f, 0.f, 0.f, 0.f};

  const float* xrow = x + (size_t)tg * 1024 + grp * 8;
  const bf16_t* wbase = wt + (size_t)(n0 + lq) * 1024 + grp * 8;

  float4 xa = *(const float4*)(xrow);
  float4 xb = *(const float4*)(xrow + 4);

  for (int ks = 0; ks < 32; ++ks) {
    int k0 = ks * 32;
    bf16x8 xf;
    xf[0] = (bf16_t)xa.x; xf[1] = (bf16_t)xa.y; xf[2] = (bf16_t)xa.z; xf[3] = (bf16_t)xa.w;
    xf[4] = (bf16_t)xb.x; xf[5] = (bf16_t)xb.y; xf[6] = (bf16_t)xb.z; xf[7] = (bf16_t)xb.w;
    // prefetch next k-step's x (wraps harmlessly on last iter)
    int kn = ((ks + 1) & 31) * 32;
    xa = *(const float4*)(xrow + kn);
    xb = *(const float4*)(xrow + kn + 4);
#pragma unroll
    for (int nf = 0; nf < 8; ++nf) {
      bf16x8 wf = *(const bf16x8*)(wbase + (size_t)(nf * 16) * 1024 + k0);
      acc[nf] = __builtin_amdgcn_mfma_f32_16x16x32_bf16(wf, xf, acc[nf], 0, 0, 0);
    }
  }

  if (slice < 2) {   // Q or K row-major
    bf16_t* dst = (slice == 0) ? q : k;
#pragma unroll
    for (int nf = 0; nf < 8; ++nf) {
      bf16x4 o;
      o[0] = (bf16_t)acc[nf][0]; o[1] = (bf16_t)acc[nf][1];
      o[2] = (bf16_t)acc[nf][2]; o[3] = (bf16_t)acc[nf][3];
      *(bf16x4*)(dst + (size_t)tg * 128 + nf * 16 + grp * 4) = o;
    }
  } else {           // V transposed: vT[b][d][t]
    int b = tg >> 11, tt = tg & 2047;
#pragma unroll
    for (int nf = 0; nf < 8; ++nf) {
#pragma unroll
      for (int r = 0; r < 4; ++r) {
        int d = nf * 16 + grp * 4 + r;
        vT[(size_t)b * 128 * 2048 + (size_t)d * 2048 + tt] = (bf16_t)acc[nf][r];
      }
    }
  }
}

// ---------------- flash attention: S^T = K·Q^T, online softmax, O^T = V^T·P^T --------
// 512 blocks (b x 64 q-tiles of 32 rows), 2 waves each; heavy tiles dispatched first.
__global__ __launch_bounds__(128) void attn_kernel(const bf16_t* __restrict__ q,
                                                   const bf16_t* __restrict__ k,
                                                   const bf16_t* __restrict__ vT,
                                                   float* __restrict__ out) {
  __shared__ __align__(16) char lds[36864];
  char* Klds = lds;                 // [64][128] bf16, XOR-swizzled rows (256B)
  char* Vlds = lds + 16384;         // [128][64] bf16, XOR-swizzled rows (128B)
  char* Plds = lds + 32768 + (threadIdx.x >> 6) * 2048;  // per-wave 2KB packed P^T

  int lane = threadIdx.x & 63;
  int wave = threadIdx.x >> 6;
  int lq = lane & 15, grp = lane >> 4;
  int b = blockIdx.x >> 6;
  int qt = 63 - (blockIdx.x & 63);  // heavy (large qt) blocks first
  int q0 = qt * 32 + wave * 16;
  int tq = q0 + lq;                 // this lane's q row

  // Q fragments (B-operand for S^T): lane lq -> q row, slots = d
  bf16x8 qf[4];
  const bf16_t* qrow = q + ((size_t)b * 2048 + tq) * 128 + grp * 8;
#pragma unroll
  for (int ks = 0; ks < 4; ++ks) qf[ks] = *(const bf16x8*)(qrow + ks * 32);

  float mrun = -__builtin_inff();
  float lsum = 0.f;
  f32x4 accO[8];
#pragma unroll
  for (int i = 0; i < 8; ++i) accO[i] = (f32x4){0.f, 0.f, 0.f, 0.f};

  const float scale = 1.0f / 32.0f;   // C^-0.5
  const char* kbase = (const char*)(k + (size_t)b * 2048 * 128);
  const char* vbase = (const char*)(vT + (size_t)b * 128 * 2048);

  int ntiles = (qt * 32 + 31) / 64 + 1;
  for (int it = 0; it < ntiles; ++it) {
    int kv0 = it * 64;
    __syncthreads();  // previous tile's compute done before overwrite
    // stage K tile [64][128] bf16: 16 x 1KB chunks, pre-swizzled global source
#pragma unroll
    for (int c = 0; c < 8; ++c) {
      int chunk = wave * 8 + c;
      int row = chunk * 4 + (lane >> 4);
      int colb = (lane & 15) * 16;
      const char* src = kbase + (size_t)(kv0 + row) * 256 + (colb ^ ((row & 7) << 4));
      g2lds16(src, Klds + chunk * 1024 + lane * 16);
    }
    // stage V^T tile [128][64] bf16
#pragma unroll
    for (int c = 0; c < 8; ++c) {
      int chunk = wave * 8 + c;
      int row = chunk * 8 + (lane >> 3);
      int colb = (lane & 7) * 16;
      const char* src = vbase + (size_t)row * 4096 + kv0 * 2 + (colb ^ ((row & 7) << 4));
      g2lds16(src, Vlds + chunk * 1024 + lane * 16);
    }
    __syncthreads();  // drains vmcnt: tiles ready

    // S^T = K · Q^T : 4 kv-frags x 4 k-steps
    f32x4 s[4];
#pragma unroll
    for (int i = 0; i < 4; ++i) s[i] = (f32x4){0.f, 0.f, 0.f, 0.f};
#pragma unroll
    for (int ks = 0; ks < 4; ++ks) {
#pragma unroll
      for (int mf = 0; mf < 4; ++mf) {
        int row = mf * 16 + lq;
        int colb = ks * 64 + grp * 16;
        bf16x8 kf = *(const bf16x8*)(Klds + row * 256 + (colb ^ ((row & 7) << 4)));
        s[mf] = __builtin_amdgcn_mfma_f32_16x16x32_bf16(kf, qf[ks], s[mf], 0, 0, 0);
      }
    }

    // online softmax; lane owns q-row tq, holds 16 kv values
    float z[4][4];
    float pmax = -__builtin_inff();
#pragma unroll
    for (int f = 0; f < 4; ++f) {
#pragma unroll
      for (int r = 0; r < 4; ++r) {
        int kv = kv0 + f * 16 + grp * 4 + r;
        float zz = s[f][r] * scale;
        zz = (kv <= tq) ? zz : -__builtin_inff();
        z[f][r] = zz;
        pmax = fmaxf(pmax, zz);
      }
    }
    pmax = fmaxf(pmax, __shfl_xor(pmax, 16, 64));
    pmax = fmaxf(pmax, __shfl_xor(pmax, 32, 64));
    float mnew = fmaxf(mrun, pmax);
    float corr = __expf(mrun - mnew);   // -inf -> 0 on first tile
    float p[4][4];
    float psum = 0.f;
#pragma unroll
    for (int f = 0; f < 4; ++f) {
#pragma unroll
      for (int r = 0; r < 4; ++r) {
        p[f][r] = __expf(z[f][r] - mnew);
        psum += p[f][r];
      }
    }
    psum += __shfl_xor(psum, 16, 64);
    psum += __shfl_xor(psum, 32, 64);
    lsum = lsum * corr + psum;
    mrun = mnew;
#pragma unroll
    for (int i = 0; i < 8; ++i) accO[i] *= corr;

    // pack P^T into wave-private LDS in exact B-operand order
#pragma unroll
    for (int f = 0; f < 4; ++f) {
      bf16x4 pw;
      pw[0] = (bf16_t)p[f][0]; pw[1] = (bf16_t)p[f][1];
      pw[2] = (bf16_t)p[f][2]; pw[3] = (bf16_t)p[f][3];
      *(bf16x4*)(Plds + ((f * 2 + (grp >> 1)) << 8) + lq * 16 + ((grp & 1) << 3)) = pw;
    }

    // O^T += V^T · P^T : 8 d-frags x 2 kv-steps
#pragma unroll
    for (int kc = 0; kc < 2; ++kc) {
      bf16x8 pf = *(const bf16x8*)(Plds + ((kc * 4 + grp) << 8) + lq * 16);
#pragma unroll
      for (int mf = 0; mf < 8; ++mf) {
        int row = mf * 16 + lq;
        int colb = kc * 64 + grp * 16;
        bf16x8 vf = *(const bf16x8*)(Vlds + row * 128 + (colb ^ ((row & 7) << 4)));
        accO[mf] = __builtin_amdgcn_mfma_f32_16x16x32_bf16(vf, pf, accO[mf], 0, 0, 0);
      }
    }
  }

  // epilogue: out[b][tq][d], d = mf*16 + grp*4 + r  -> float4 stores
  float inv = 1.0f / lsum;
  float* orow = out + ((size_t)b * 2048 + tq) * 128;
#pragma unroll
  for (int mf = 0; mf < 8; ++mf) {
    f32x4 o;
    o[0] = accO[mf][0] * inv; o[1] = accO[mf][1] * inv;
    o[2] = accO[mf][2] * inv; o[3] = accO[mf][3] * inv;
    *(f32x4*)(orow + mf * 16 + grp * 4) = o;
  }
}

extern "C" void kernel_launch(void* const* d_in, const int* in_sizes, int n_in,
                              void* d_out, int out_size, void* d_ws, size_t ws_size,
                              hipStream_t stream) {
  const float* x  = (const float*)d_in[0];
  const float* Wq = (const float*)d_in[1];
  const float* Wk = (const float*)d_in[2];
  const float* Wv = (const float*)d_in[3];
  float* out = (float*)d_out;
  char* ws = (char*)d_ws;

  bf16_t* wt = (bf16_t*)(ws + WT_OFF);
  bf16_t* qb = (bf16_t*)(ws + Q_OFF);
  bf16_t* kb = (bf16_t*)(ws + K_OFF);
  bf16_t* vT = (bf16_t*)(ws + VT_OFF);

  hipLaunchKernelGGL(wt_kernel, dim3(48), dim3(256), 0, stream, Wq, Wk, Wv, wt);
  hipLaunchKernelGGL(proj_kernel, dim3(768), dim3(256), 0, stream, x, wt, qb, kb, vT);
  hipLaunchKernelGGL(attn_kernel, dim3(512), dim3(128), 0, stream, qb, kb, vT, out);
}